// Round 1
// 883.861 us; speedup vs baseline: 4.0010x; 4.0010x over previous
//
#include <hip/hip_runtime.h>
#include <stdint.h>

#define FMAPD 56
#define WSD 7
#define SHIFTD 3
#define LD 49      // tokens per window
#define CD 96      // hidden
#define NHD 3
#define HDD 32     // head dim

using u16 = unsigned short;
using u32 = unsigned int;

typedef __attribute__((ext_vector_type(8))) short bh8;   // 8 bf16 (4 VGPRs) MFMA A/B frag
typedef __attribute__((ext_vector_type(4))) float f4;    // MFMA C/D frag

__device__ __forceinline__ u16 f2b(float f) {
  union { float f; u32 i; } v; v.f = f;
  u32 r = v.i + 0x7fffu + ((v.i >> 16) & 1u);   // RNE
  return (u16)(r >> 16);
}

// LDS strides (u16 elements) chosen so row-start banks spread 8-wide (2-way conflict = free)
#define SH 104   // s_h   [64][104]  (96 cols used)
#define SS 200   // s_sc  [64][200]  (Q,K: 192 cols; later FFN hidden 192)
#define SV 72    // s_vt  [96][72]   (V transposed: [h*32+d][token], 64 used)
#define SP 72    // s_p   [4][16][72] (per-wave P tile, 64 used)

// ---- prepass: convert the 4 weight matrices to bf16 in workspace ----
// layout in ws (u16): qkv_w[27648] | out_w[9216] | ff1_w[36864] | ff2_w[36864]  = 221,184 B
__global__ void cvt_weights(const float* __restrict__ a, const float* __restrict__ b,
                            const float* __restrict__ c, const float* __restrict__ d,
                            u16* __restrict__ ws) {
  int i = blockIdx.x * 256 + threadIdx.x;
  if (i < 27648)       ws[i] = f2b(a[i]);
  else if (i < 36864)  ws[i] = f2b(b[i - 27648]);
  else if (i < 73728)  ws[i] = f2b(c[i - 36864]);
  else if (i < 110592) ws[i] = f2b(d[i - 73728]);
}

__global__ __launch_bounds__(256, 2)
void swin_mfma(const float* __restrict__ gx,
               const float* __restrict__ b_qkv,
               const float* __restrict__ b_out,
               const float* __restrict__ w_ln1, const float* __restrict__ b_ln1,
               const float* __restrict__ w_ln2, const float* __restrict__ b_ln2,
               const float* __restrict__ b_ff1, const float* __restrict__ b_ff2,
               const u16* __restrict__ ws,
               float* __restrict__ gout)
{
  __shared__ __align__(16) u16 s_h [64 * SH];       // LN out -> A frags; later attn-out o
  __shared__ __align__(16) u16 s_sc[64 * SS];       // Q|K (cols 0..191); later FFN hidden
  __shared__ __align__(16) u16 s_vt[3 * 32 * SV];   // V^T per head
  __shared__ __align__(16) u16 s_p [4 * 16 * SP];   // per-wave P tile (16 x 64)
  __shared__ int s_id[64];

  const int tid = threadIdx.x;
  const int w = tid >> 6, lane = tid & 63, g = lane >> 4, lq = lane & 15;
  const int blk = blockIdx.x, b = blk >> 6, wr = (blk >> 3) & 7, wc = blk & 7;

  const u16* wsq = ws;            // [288][96]
  const u16* wso = ws + 27648;    // [96][96]
  const u16* wf1 = ws + 36864;    // [384][96]
  const u16* wf2 = ws + 73728;    // [96][384]

  // region ids for the shifted-window mask (tokens >=49 get -1 => masked vs all valid)
  if (tid < 64) {
    int id = -1;
    if (tid < 49) {
      int i = tid / 7, j = tid - 7 * i;
      int rp = wr * 7 + i, cp = wc * 7 + j;
      int ri = (rp < 49) ? 0 : ((rp < 53) ? 1 : 2);
      int ci = (cp < 49) ? 0 : ((cp < 53) ? 1 : 2);
      id = ri * 3 + ci;
    }
    s_id[tid] = id;
  }

  // ---- load x into residual registers, C-fragment layout:
  // resid[t][r] = xw[row = 16w + 4g + r][col = 16t + lq]
  float resid[6][4];
  size_t gbase[4];
  bool tval[4];
#pragma unroll
  for (int r = 0; r < 4; ++r) {
    int token = 16 * w + 4 * g + r;
    tval[r] = token < LD;
    int ti = token / 7, tj = token - 7 * ti;
    int row = wr * 7 + ti + SHIFTD; if (row >= FMAPD) row -= FMAPD;
    int col = wc * 7 + tj + SHIFTD; if (col >= FMAPD) col -= FMAPD;
    gbase[r] = ((size_t)b * (FMAPD * FMAPD) + row * FMAPD + col) * (size_t)CD + lq;
#pragma unroll
    for (int t = 0; t < 6; ++t) {
      float v = gx[gbase[r] + 16 * t];
      resid[t][r] = tval[r] ? v : 0.f;
    }
  }

  // in-register LayerNorm over the trunk -> bf16 into s_h (wave-private rows)
  auto layer_norm = [&](const float* lw, const float* lb) {
    float wv[6], bv[6];
#pragma unroll
    for (int t = 0; t < 6; ++t) { wv[t] = lw[16 * t + lq]; bv[t] = lb[16 * t + lq]; }
#pragma unroll
    for (int r = 0; r < 4; ++r) {
      float s = 0.f, s2 = 0.f;
#pragma unroll
      for (int t = 0; t < 6; ++t) { float v = resid[t][r]; s += v; s2 += v * v; }
#pragma unroll
      for (int m = 1; m <= 8; m <<= 1) { s += __shfl_xor(s, m, 64); s2 += __shfl_xor(s2, m, 64); }
      float mu = s * (1.f / 96.f);
      float rs = rsqrtf(s2 * (1.f / 96.f) - mu * mu + 1e-5f);
      u16* dst = s_h + (16 * w + 4 * g + r) * SH;
#pragma unroll
      for (int t = 0; t < 6; ++t) dst[16 * t + lq] = f2b((resid[t][r] - mu) * rs * wv[t] + bv[t]);
    }
  };
  layer_norm(w_ln1, b_ln1);

  // ---- QKV GEMM: [16x96] @ [96x288]^T-stored. A from s_h (own rows), B from ws.
  {
    const u16* arow = s_h + (16 * w + lq) * SH;
    bh8 af[3];
#pragma unroll
    for (int kk = 0; kk < 3; ++kk) af[kk] = *(const bh8*)(arow + 32 * kk + 8 * g);
    // Q,K tiles -> s_sc
#pragma unroll 3
    for (int t = 0; t < 12; ++t) {
      int n = 16 * t + lq;
      f4 acc = {0.f, 0.f, 0.f, 0.f};
#pragma unroll
      for (int kk = 0; kk < 3; ++kk) {
        bh8 bf = *(const bh8*)(wsq + n * CD + 32 * kk + 8 * g);
        acc = __builtin_amdgcn_mfma_f32_16x16x32_bf16(af[kk], bf, acc, 0, 0, 0);
      }
      float bias = b_qkv[n];
      u16* dst = s_sc + (16 * w + 4 * g) * SS + n;
#pragma unroll
      for (int r = 0; r < 4; ++r) dst[r * SS] = f2b(acc[r] + bias);
    }
    // V tiles -> s_vt transposed
#pragma unroll 3
    for (int t = 12; t < 18; ++t) {
      int n = 16 * t + lq;
      f4 acc = {0.f, 0.f, 0.f, 0.f};
#pragma unroll
      for (int kk = 0; kk < 3; ++kk) {
        bh8 bf = *(const bh8*)(wsq + n * CD + 32 * kk + 8 * g);
        acc = __builtin_amdgcn_mfma_f32_16x16x32_bf16(af[kk], bf, acc, 0, 0, 0);
      }
      float bias = b_qkv[n];
      int nn = n - 192;                      // 0..95 -> head h, dim d
      u16* dst = s_vt + nn * SV + 16 * w + 4 * g;
#pragma unroll
      for (int r = 0; r < 4; ++r) dst[r] = f2b(acc[r] + bias);
    }
  }
  __syncthreads();   // barrier 1: s_sc / s_vt / s_id visible to all waves

  // ---- attention (per head): QK^T in-register, parallel softmax, P->LDS, PV
  const float scale = 0.17677669529663687f;  // 1/sqrt(32)
  int rid[4], cid[4];
#pragma unroll
  for (int r = 0; r < 4; ++r) rid[r] = s_id[16 * w + 4 * g + r];
#pragma unroll
  for (int t = 0; t < 4; ++t) cid[t] = s_id[16 * t + lq];

  for (int hh = 0; hh < NHD; ++hh) {
    bh8 qa = *(const bh8*)(s_sc + (16 * w + lq) * SS + hh * 32 + 8 * g);
    f4 sc[4];
#pragma unroll
    for (int t = 0; t < 4; ++t) {
      bh8 kb = *(const bh8*)(s_sc + (16 * t + lq) * SS + CD + hh * 32 + 8 * g);
      f4 z = {0.f, 0.f, 0.f, 0.f};
      sc[t] = __builtin_amdgcn_mfma_f32_16x16x32_bf16(qa, kb, z, 0, 0, 0);
    }
#pragma unroll
    for (int t = 0; t < 4; ++t)
#pragma unroll
      for (int r = 0; r < 4; ++r) {
        float v = sc[t][r] * scale;
        if (rid[r] != cid[t]) v -= 1e9f;
        sc[t][r] = v;
      }
    // row softmax: in-lane over 4 tiles, then shfl over the 16-lane group
    float pr[4][4];
#pragma unroll
    for (int r = 0; r < 4; ++r) {
      float mx = fmaxf(fmaxf(sc[0][r], sc[1][r]), fmaxf(sc[2][r], sc[3][r]));
#pragma unroll
      for (int m = 1; m <= 8; m <<= 1) mx = fmaxf(mx, __shfl_xor(mx, m, 64));
      float den = 0.f;
#pragma unroll
      for (int t = 0; t < 4; ++t) { float e = __expf(sc[t][r] - mx); pr[t][r] = e; den += e; }
#pragma unroll
      for (int m = 1; m <= 8; m <<= 1) den += __shfl_xor(den, m, 64);
      float inv = 1.0f / den;
#pragma unroll
      for (int t = 0; t < 4; ++t) pr[t][r] *= inv;
    }
    // write P (wave-private 16x64 tile)
    u16* pw = s_p + w * (16 * SP) + (4 * g) * SP;
#pragma unroll
    for (int t = 0; t < 4; ++t)
#pragma unroll
      for (int r = 0; r < 4; ++r) pw[r * SP + 16 * t + lq] = f2b(pr[t][r]);
    // PV: A = P (own tile), B^T = V^T slice
    const u16* prow = s_p + w * (16 * SP) + lq * SP;
    bh8 pa0 = *(const bh8*)(prow + 8 * g);
    bh8 pa1 = *(const bh8*)(prow + 32 + 8 * g);
#pragma unroll
    for (int nt = 0; nt < 2; ++nt) {
      const u16* vrow = s_vt + (hh * 32 + 16 * nt + lq) * SV;
      bh8 vb0 = *(const bh8*)(vrow + 8 * g);
      bh8 vb1 = *(const bh8*)(vrow + 32 + 8 * g);
      f4 oacc = {0.f, 0.f, 0.f, 0.f};
      oacc = __builtin_amdgcn_mfma_f32_16x16x32_bf16(pa0, vb0, oacc, 0, 0, 0);
      oacc = __builtin_amdgcn_mfma_f32_16x16x32_bf16(pa1, vb1, oacc, 0, 0, 0);
      u16* dst = s_h + (16 * w + 4 * g) * SH + hh * 32 + 16 * nt + lq;
#pragma unroll
      for (int r = 0; r < 4; ++r) dst[r * SH] = f2b(oacc[r]);
    }
  }
  __syncthreads();   // barrier 2: all QK^T reads of s_sc done before FFN overwrites it

  // ---- out-projection: resid += o @ out_w^T + b
  {
    const u16* orow = s_h + (16 * w + lq) * SH;
    bh8 oa[3];
#pragma unroll
    for (int kk = 0; kk < 3; ++kk) oa[kk] = *(const bh8*)(orow + 32 * kk + 8 * g);
#pragma unroll 3
    for (int t = 0; t < 6; ++t) {
      int n = 16 * t + lq;
      f4 acc = {0.f, 0.f, 0.f, 0.f};
#pragma unroll
      for (int kk = 0; kk < 3; ++kk) {
        bh8 bf = *(const bh8*)(wso + n * CD + 32 * kk + 8 * g);
        acc = __builtin_amdgcn_mfma_f32_16x16x32_bf16(oa[kk], bf, acc, 0, 0, 0);
      }
      float bias = b_out[n];
#pragma unroll
      for (int r = 0; r < 4; ++r) resid[t][r] += acc[r] + bias;
    }
  }

  layer_norm(w_ln2, b_ln2);

  // ---- FFN in two 192-wide halves; hidden lives in s_sc (wave-private rows)
  {
    const u16* hrow = s_h + (16 * w + lq) * SH;
    bh8 ha[3];
#pragma unroll
    for (int kk = 0; kk < 3; ++kk) ha[kk] = *(const bh8*)(hrow + 32 * kk + 8 * g);
    const u16* frow = s_sc + (16 * w + lq) * SS;
#pragma unroll 1
    for (int half = 0; half < 2; ++half) {
      // FF1 + exact GELU
#pragma unroll 3
      for (int t = 0; t < 12; ++t) {
        int n = 192 * half + 16 * t + lq;
        f4 acc = {0.f, 0.f, 0.f, 0.f};
#pragma unroll
        for (int kk = 0; kk < 3; ++kk) {
          bh8 bf = *(const bh8*)(wf1 + n * CD + 32 * kk + 8 * g);
          acc = __builtin_amdgcn_mfma_f32_16x16x32_bf16(ha[kk], bf, acc, 0, 0, 0);
        }
        float bias = b_ff1[n];
        u16* dst = s_sc + (16 * w + 4 * g) * SS + 16 * t + lq;
#pragma unroll
        for (int r = 0; r < 4; ++r) {
          float v = acc[r] + bias;
          float ge = 0.5f * v * (1.0f + erff(v * 0.70710678118654752f));
          dst[r * SS] = f2b(ge);
        }
      }
      // FF2: resid += gelu(h) @ ff2_w^T (+ bias once)
      bh8 fa[6];
#pragma unroll
      for (int ks = 0; ks < 6; ++ks) fa[ks] = *(const bh8*)(frow + 32 * ks + 8 * g);
#pragma unroll 3
      for (int t = 0; t < 6; ++t) {
        int n = 16 * t + lq;
        f4 acc = {0.f, 0.f, 0.f, 0.f};
#pragma unroll
        for (int ks = 0; ks < 6; ++ks) {
          bh8 bf = *(const bh8*)(wf2 + n * 384 + 192 * half + 32 * ks + 8 * g);
          acc = __builtin_amdgcn_mfma_f32_16x16x32_bf16(fa[ks], bf, acc, 0, 0, 0);
        }
        float bias = half ? 0.f : b_ff2[n];
#pragma unroll
        for (int r = 0; r < 4; ++r) resid[t][r] += acc[r] + bias;
      }
    }
  }

  // ---- store trunk back (fp32), reverse window/shift mapping
#pragma unroll
  for (int r = 0; r < 4; ++r) {
    if (tval[r]) {
#pragma unroll
      for (int t = 0; t < 6; ++t) gout[gbase[r] + 16 * t] = resid[t][r];
    }
  }
}

extern "C" void kernel_launch(void* const* d_in, const int* in_sizes, int n_in,
                              void* d_out, int out_size, void* d_ws, size_t ws_size,
                              hipStream_t stream) {
  // prepass: bf16 weights into workspace (221,184 B)
  cvt_weights<<<432, 256, 0, stream>>>(
      (const float*)d_in[1], (const float*)d_in[3],
      (const float*)d_in[9], (const float*)d_in[11], (u16*)d_ws);
  swin_mfma<<<8192, 256, 0, stream>>>(
      (const float*)d_in[0],                     // x
      (const float*)d_in[2],                     // qkv_b
      (const float*)d_in[4],                     // out_b
      (const float*)d_in[5], (const float*)d_in[6],   // ln1
      (const float*)d_in[7], (const float*)d_in[8],   // ln2
      (const float*)d_in[10], (const float*)d_in[12], // ff1_b, ff2_b
      (const u16*)d_ws, (float*)d_out);
}

// Round 2
// 876.792 us; speedup vs baseline: 4.0332x; 1.0081x over previous
//
#include <hip/hip_runtime.h>
#include <stdint.h>

#define FMAPD 56
#define LD 49      // tokens per window
#define CD 96      // hidden

using u16 = unsigned short;
using u32 = unsigned int;

typedef __attribute__((ext_vector_type(8))) short bh8;   // 8 bf16 MFMA A/B frag
typedef __attribute__((ext_vector_type(4))) float f4;    // MFMA C/D frag

__device__ __forceinline__ u16 f2b(float f) {
  union { float f; u32 i; } v; v.f = f;
  u32 r = v.i + 0x7fffu + ((v.i >> 16) & 1u);   // RNE
  return (u16)(r >> 16);
}
__device__ __forceinline__ u32 pk2(float a, float b) {
  return (u32)f2b(a) | ((u32)f2b(b) << 16);
}

// exact-GELU via A&S 7.1.26 erf (|err| < 1.5e-7), branchless
__device__ __forceinline__ float gelu_f(float v) {
  float x = fabsf(v) * 0.70710678118654752f;
  float t = __builtin_amdgcn_rcpf(fmaf(x, 0.3275911f, 1.0f));
  float p = fmaf(t, 1.061405429f, -1.453152027f);
  p = fmaf(p, t, 1.421413741f);
  p = fmaf(p, t, -0.284496736f);
  p = fmaf(p, t, 0.254829592f);
  p = p * t;
  float e = __expf(-x * x);
  float q = 0.5f * p * e;                     // Phi(-|x|)
  float phi = (v >= 0.0f) ? (1.0f - q) : q;
  return v * phi;
}

// LDS strides (u16 elements)
#define SH 104   // s_h / s_k row stride (96 used); 208B rows
#define SV 72    // s_vt row stride (64 used); 144B rows (16B aligned)
#define SP 104   // per-wave scratch row stride

// ---- prepass: convert the 4 weight matrices to bf16 in workspace ----
__global__ void cvt_weights(const float* __restrict__ a, const float* __restrict__ b,
                            const float* __restrict__ c, const float* __restrict__ d,
                            u16* __restrict__ ws) {
  int i = blockIdx.x * 256 + threadIdx.x;
  if (i < 27648)       ws[i] = f2b(a[i]);
  else if (i < 36864)  ws[i] = f2b(b[i - 27648]);
  else if (i < 73728)  ws[i] = f2b(c[i - 36864]);
  else if (i < 110592) ws[i] = f2b(d[i - 73728]);
}

__global__ __launch_bounds__(256, 3)
void swin_mfma(const float* __restrict__ gx,
               const float* __restrict__ b_qkv,
               const float* __restrict__ b_out,
               const float* __restrict__ w_ln1, const float* __restrict__ b_ln1,
               const float* __restrict__ w_ln2, const float* __restrict__ b_ln2,
               const float* __restrict__ b_ff1, const float* __restrict__ b_ff2,
               const u16* __restrict__ ws,
               float* __restrict__ gout)
{
  // 13312 + 13312 + 13824 + 13312 + 256 = 54,016 B -> 3 blocks/CU
  __shared__ __align__(16) u16 s_h [64 * SH];      // LN out; later attn-out o
  __shared__ __align__(16) u16 s_k [64 * SH];      // K rows; later FFN hidden quarter
  __shared__ __align__(16) u16 s_vt[96 * SV];      // V^T [d][token]
  __shared__ __align__(16) u16 s_p [4 * 16 * SP];  // per-wave Q / P scratch
  __shared__ __align__(16) int s_id[64];

  const int tid = threadIdx.x;
  const int w = tid >> 6, lane = tid & 63, g = lane >> 4, lq = lane & 15;
  const int blk = blockIdx.x, b = blk >> 6, wr = (blk >> 3) & 7, wc = blk & 7;

  const u16* wsq = ws;            // [288][96]
  const u16* wso = ws + 27648;    // [96][96]
  const u16* wf1 = ws + 36864;    // [384][96]
  const u16* wf2 = ws + 73728;    // [96][384]

  u16* s_pw = s_p + w * (16 * SP);

  if (tid < 64) {
    int id = -1;
    if (tid < 49) {
      int i = tid / 7, j = tid - 7 * i;
      int rp = wr * 7 + i, cp = wc * 7 + j;
      int ri = (rp < 49) ? 0 : ((rp < 53) ? 1 : 2);
      int ci = (cp < 49) ? 0 : ((cp < 53) ? 1 : 2);
      id = ri * 3 + ci;
    }
    s_id[tid] = id;
  }

  // ---- x -> residual registers, C-fragment layout: resid[t][r] = x[16w+4g+r][16t+lq]
  float resid[6][4];
  size_t gbase[4];
  bool tval[4];
#pragma unroll
  for (int r = 0; r < 4; ++r) {
    int token = 16 * w + 4 * g + r;
    tval[r] = token < LD;
    int ti = token / 7, tj = token - 7 * ti;
    int row = wr * 7 + ti + 3; if (row >= FMAPD) row -= FMAPD;
    int col = wc * 7 + tj + 3; if (col >= FMAPD) col -= FMAPD;
    gbase[r] = ((size_t)b * (FMAPD * FMAPD) + row * FMAPD + col) * (size_t)CD + lq;
#pragma unroll
    for (int t = 0; t < 6; ++t) {
      float v = gx[gbase[r] + 16 * t];
      resid[t][r] = tval[r] ? v : 0.f;
    }
  }

  // ---- bias preloads (issued early; all L2-resident)
  float bq[6][4];                      // Q bias, g-sliced: b_qkv[16t+4g+r]
#pragma unroll
  for (int t = 0; t < 6; ++t) {
    float4 v = *(const float4*)(b_qkv + 16 * t + 4 * g);
    bq[t][0] = v.x; bq[t][1] = v.y; bq[t][2] = v.z; bq[t][3] = v.w;
  }
  float bvv[6], bov[6], bf2v[6];
#pragma unroll
  for (int t = 0; t < 6; ++t) {
    bvv[t]  = b_qkv[192 + 16 * t + lq];
    bov[t]  = b_out[16 * t + lq];
    bf2v[t] = b_ff2[16 * t + lq];
  }

  // in-register LayerNorm -> bf16 rows in s_h (wave-private)
  auto layer_norm = [&](const float* lw, const float* lb) {
    float wv[6], bv[6];
#pragma unroll
    for (int t = 0; t < 6; ++t) { wv[t] = lw[16 * t + lq]; bv[t] = lb[16 * t + lq]; }
#pragma unroll
    for (int r = 0; r < 4; ++r) {
      float s = 0.f, s2 = 0.f;
#pragma unroll
      for (int t = 0; t < 6; ++t) { float v = resid[t][r]; s += v; s2 += v * v; }
#pragma unroll
      for (int m = 1; m <= 8; m <<= 1) { s += __shfl_xor(s, m, 64); s2 += __shfl_xor(s2, m, 64); }
      float mu = s * (1.f / 96.f);
      float rs = rsqrtf(s2 * (1.f / 96.f) - mu * mu + 1e-5f);
      u16* dst = s_h + (16 * w + 4 * g + r) * SH;
#pragma unroll
      for (int t = 0; t < 6; ++t) dst[16 * t + lq] = f2b((resid[t][r] - mu) * rs * wv[t] + bv[t]);
    }
  };
  layer_norm(w_ln1, b_ln1);

  // ---- QKV. Swapped-operand MFMAs give transposed C tiles -> packed b64 stores.
  {
    const u16* arow = s_h + (16 * w + lq) * SH;
    bh8 af[3];
#pragma unroll
    for (int kk = 0; kk < 3; ++kk) af[kk] = *(const bh8*)(arow + 32 * kk + 8 * g);

    // Q (swapped): lane holds Q[i=16w+lq][d=16t+4g+r] -> s_p rows lq
#pragma unroll
    for (int t = 0; t < 6; ++t) {
      f4 acc = {0.f, 0.f, 0.f, 0.f};
#pragma unroll
      for (int kk = 0; kk < 3; ++kk) {
        bh8 bf = *(const bh8*)(wsq + (16 * t + lq) * CD + 32 * kk + 8 * g);
        acc = __builtin_amdgcn_mfma_f32_16x16x32_bf16(bf, af[kk], acc, 0, 0, 0);
      }
      uint2 u; u.x = pk2(acc[0] + bq[t][0], acc[1] + bq[t][1]);
      u.y = pk2(acc[2] + bq[t][2], acc[3] + bq[t][3]);
      *(uint2*)(s_pw + lq * SP + 16 * t + 4 * g) = u;
    }
    // K (swapped, NO bias: a per-row constant in Q.K^T cancels in softmax) -> s_k
#pragma unroll
    for (int t = 0; t < 6; ++t) {
      f4 acc = {0.f, 0.f, 0.f, 0.f};
#pragma unroll
      for (int kk = 0; kk < 3; ++kk) {
        bh8 bf = *(const bh8*)(wsq + (96 + 16 * t + lq) * CD + 32 * kk + 8 * g);
        acc = __builtin_amdgcn_mfma_f32_16x16x32_bf16(bf, af[kk], acc, 0, 0, 0);
      }
      uint2 u; u.x = pk2(acc[0], acc[1]); u.y = pk2(acc[2], acc[3]);
      *(uint2*)(s_k + (16 * w + lq) * SH + 16 * t + 4 * g) = u;
    }
    // V (unswapped): lane holds V[tok=16w+4g+r][d=16t+lq] -> V^T rows, packed
#pragma unroll
    for (int t = 0; t < 6; ++t) {
      f4 acc = {0.f, 0.f, 0.f, 0.f};
#pragma unroll
      for (int kk = 0; kk < 3; ++kk) {
        bh8 bf = *(const bh8*)(wsq + (192 + 16 * t + lq) * CD + 32 * kk + 8 * g);
        acc = __builtin_amdgcn_mfma_f32_16x16x32_bf16(af[kk], bf, acc, 0, 0, 0);
      }
      float bias = bvv[t];
      uint2 u; u.x = pk2(acc[0] + bias, acc[1] + bias);
      u.y = pk2(acc[2] + bias, acc[3] + bias);
      *(uint2*)(s_vt + (16 * t + lq) * SV + 16 * w + 4 * g) = u;
    }
  }
  // Q fragments for all heads (wave-private; before P overwrites s_p)
  bh8 qa[3];
#pragma unroll
  for (int hh = 0; hh < 3; ++hh) qa[hh] = *(const bh8*)(s_pw + lq * SP + 32 * hh + 8 * g);

  __syncthreads();   // barrier 1: s_k / s_vt / s_id visible to all waves

  // ---- attention: swapped QK^T puts a full score row in each lane-quad
  const int id_i = s_id[16 * w + lq];
  int idj[4][4];
#pragma unroll
  for (int t = 0; t < 4; ++t) {
    int4 v = *(const int4*)(s_id + 16 * t + 4 * g);
    idj[t][0] = v.x; idj[t][1] = v.y; idj[t][2] = v.z; idj[t][3] = v.w;
  }
  const float scale = 0.17677669529663687f;  // 1/sqrt(32)

#pragma unroll
  for (int hh = 0; hh < 3; ++hh) {
    f4 sc[4];
#pragma unroll
    for (int t = 0; t < 4; ++t) {
      bh8 kb = *(const bh8*)(s_k + (16 * t + lq) * SH + 32 * hh + 8 * g);
      f4 z = {0.f, 0.f, 0.f, 0.f};
      sc[t] = __builtin_amdgcn_mfma_f32_16x16x32_bf16(kb, qa[hh], z, 0, 0, 0);
    }
    // lane holds S[i=16w+lq][j=16t+4g+r]; reduce in-lane + shfl_xor(16,32)
    float pv[4][4];
    float mx = -3.0e38f;
#pragma unroll
    for (int t = 0; t < 4; ++t)
#pragma unroll
      for (int r = 0; r < 4; ++r) {
        float v = sc[t][r] * scale;
        v = (id_i != idj[t][r]) ? v - 1e9f : v;
        pv[t][r] = v;
        mx = fmaxf(mx, v);
      }
    mx = fmaxf(mx, __shfl_xor(mx, 16, 64));
    mx = fmaxf(mx, __shfl_xor(mx, 32, 64));
    float den = 0.f;
#pragma unroll
    for (int t = 0; t < 4; ++t)
#pragma unroll
      for (int r = 0; r < 4; ++r) { float e = __expf(pv[t][r] - mx); pv[t][r] = e; den += e; }
    den += __shfl_xor(den, 16, 64);
    den += __shfl_xor(den, 32, 64);
    float inv = 1.0f / den;
    // P -> s_p rows lq (overwrites Q cols 0..63; qa already in regs)
#pragma unroll
    for (int t = 0; t < 4; ++t) {
      uint2 u; u.x = pk2(pv[t][0] * inv, pv[t][1] * inv);
      u.y = pk2(pv[t][2] * inv, pv[t][3] * inv);
      *(uint2*)(s_pw + lq * SP + 16 * t + 4 * g) = u;
    }
    bh8 pa0 = *(const bh8*)(s_pw + lq * SP + 8 * g);
    bh8 pa1 = *(const bh8*)(s_pw + lq * SP + 32 + 8 * g);
    // PV swapped: lane holds o[i=16w+lq][d=32hh+16nt+4g+r] -> packed b64 into s_h
#pragma unroll
    for (int nt = 0; nt < 2; ++nt) {
      const u16* vrow = s_vt + (32 * hh + 16 * nt + lq) * SV;
      bh8 vb0 = *(const bh8*)(vrow + 8 * g);
      bh8 vb1 = *(const bh8*)(vrow + 32 + 8 * g);
      f4 o = {0.f, 0.f, 0.f, 0.f};
      o = __builtin_amdgcn_mfma_f32_16x16x32_bf16(vb0, pa0, o, 0, 0, 0);
      o = __builtin_amdgcn_mfma_f32_16x16x32_bf16(vb1, pa1, o, 0, 0, 0);
      uint2 u; u.x = pk2(o[0], o[1]); u.y = pk2(o[2], o[3]);
      *(uint2*)(s_h + (16 * w + lq) * SH + 32 * hh + 16 * nt + 4 * g) = u;
    }
  }

  // ---- out-projection (unswapped, into residual); wave-private rows of s_h
  {
    const u16* orow = s_h + (16 * w + lq) * SH;
    bh8 oa[3];
#pragma unroll
    for (int kk = 0; kk < 3; ++kk) oa[kk] = *(const bh8*)(orow + 32 * kk + 8 * g);
#pragma unroll
    for (int t = 0; t < 6; ++t) {
      f4 acc = {0.f, 0.f, 0.f, 0.f};
#pragma unroll
      for (int kk = 0; kk < 3; ++kk) {
        bh8 bf = *(const bh8*)(wso + (16 * t + lq) * CD + 32 * kk + 8 * g);
        acc = __builtin_amdgcn_mfma_f32_16x16x32_bf16(oa[kk], bf, acc, 0, 0, 0);
      }
#pragma unroll
      for (int r = 0; r < 4; ++r) resid[t][r] += acc[r] + bov[t];
    }
  }

  layer_norm(w_ln2, b_ln2);
  // fold FF2 bias into the trunk once (after LN2 has consumed resid)
#pragma unroll
  for (int t = 0; t < 6; ++t)
#pragma unroll
    for (int r = 0; r < 4; ++r) resid[t][r] += bf2v[t];

  __syncthreads();   // barrier 2: all cross-wave K reads done before FFN reuses s_k

  // ---- FFN in 4 quarters of 96; hidden quarter lives in s_k (wave-private rows)
  {
    const u16* hrow = s_h + (16 * w + lq) * SH;
    bh8 ha[3];
#pragma unroll
    for (int kk = 0; kk < 3; ++kk) ha[kk] = *(const bh8*)(hrow + 32 * kk + 8 * g);
    const u16* frow = s_k + (16 * w + lq) * SH;
#pragma unroll 1
    for (int qq = 0; qq < 4; ++qq) {
      float bq1[6][4];                 // g-sliced FF1 bias for this quarter
#pragma unroll
      for (int t = 0; t < 6; ++t) {
        float4 v = *(const float4*)(b_ff1 + 96 * qq + 16 * t + 4 * g);
        bq1[t][0] = v.x; bq1[t][1] = v.y; bq1[t][2] = v.z; bq1[t][3] = v.w;
      }
      // FF1 (swapped) + GELU: lane holds hid[i=16w+lq][f=16t+4g+r] -> packed b64
#pragma unroll
      for (int t = 0; t < 6; ++t) {
        f4 acc = {0.f, 0.f, 0.f, 0.f};
#pragma unroll
        for (int kk = 0; kk < 3; ++kk) {
          bh8 bf = *(const bh8*)(wf1 + (96 * qq + 16 * t + lq) * CD + 32 * kk + 8 * g);
          acc = __builtin_amdgcn_mfma_f32_16x16x32_bf16(bf, ha[kk], acc, 0, 0, 0);
        }
        uint2 u;
        u.x = pk2(gelu_f(acc[0] + bq1[t][0]), gelu_f(acc[1] + bq1[t][1]));
        u.y = pk2(gelu_f(acc[2] + bq1[t][2]), gelu_f(acc[3] + bq1[t][3]));
        *(uint2*)(s_k + (16 * w + lq) * SH + 16 * t + 4 * g) = u;
      }
      bh8 fa[3];
#pragma unroll
      for (int ks = 0; ks < 3; ++ks) fa[ks] = *(const bh8*)(frow + 32 * ks + 8 * g);
      // FF2 (unswapped) into residual
#pragma unroll
      for (int t = 0; t < 6; ++t) {
        f4 acc = {0.f, 0.f, 0.f, 0.f};
#pragma unroll
        for (int ks = 0; ks < 3; ++ks) {
          bh8 bf = *(const bh8*)(wf2 + (16 * t + lq) * 384 + 96 * qq + 32 * ks + 8 * g);
          acc = __builtin_amdgcn_mfma_f32_16x16x32_bf16(fa[ks], bf, acc, 0, 0, 0);
        }
#pragma unroll
        for (int r = 0; r < 4; ++r) resid[t][r] += acc[r];
      }
    }
  }

  // ---- store trunk (fp32), reverse window/shift mapping
#pragma unroll
  for (int r = 0; r < 4; ++r) {
    if (tval[r]) {
#pragma unroll
      for (int t = 0; t < 6; ++t) gout[gbase[r] + 16 * t] = resid[t][r];
    }
  }
}

extern "C" void kernel_launch(void* const* d_in, const int* in_sizes, int n_in,
                              void* d_out, int out_size, void* d_ws, size_t ws_size,
                              hipStream_t stream) {
  cvt_weights<<<432, 256, 0, stream>>>(
      (const float*)d_in[1], (const float*)d_in[3],
      (const float*)d_in[9], (const float*)d_in[11], (u16*)d_ws);
  swin_mfma<<<8192, 256, 0, stream>>>(
      (const float*)d_in[0],                          // x
      (const float*)d_in[2],                          // qkv_b
      (const float*)d_in[4],                          // out_b
      (const float*)d_in[5], (const float*)d_in[6],   // ln1
      (const float*)d_in[7], (const float*)d_in[8],   // ln2
      (const float*)d_in[10], (const float*)d_in[12], // ff1_b, ff2_b
      (const u16*)d_ws, (float*)d_out);
}

// Round 4
// 815.921 us; speedup vs baseline: 4.3341x; 1.0746x over previous
//
#include <hip/hip_runtime.h>
#include <stdint.h>

#define FMAPD 56
#define LD 49      // tokens per window
#define CD 96      // hidden

using u16 = unsigned short;
using u32 = unsigned int;

typedef __attribute__((ext_vector_type(8))) short bh8;   // 8 bf16 MFMA A/B frag
typedef __attribute__((ext_vector_type(4))) float f4;    // MFMA C/D frag
typedef __attribute__((ext_vector_type(2))) unsigned int uv2;

__device__ __forceinline__ u16 f2b(float f) {
  union { float f; u32 i; } v; v.f = f;
  u32 r = v.i + 0x7fffu + ((v.i >> 16) & 1u);   // RNE
  return (u16)(r >> 16);
}
__device__ __forceinline__ u32 pk2(float a, float b) {
  return (u32)f2b(a) | ((u32)f2b(b) << 16);
}
__device__ __forceinline__ bh8 mk8(u32 a, u32 b, u32 c, u32 d) {
  union { u32 u[4]; bh8 v; } x;
  x.u[0] = a; x.u[1] = b; x.u[2] = c; x.u[3] = d;
  return x.v;
}
// 2^x via v_exp_f32 (exact hw exp2)
__device__ __forceinline__ float ex2(float x) { return __builtin_amdgcn_exp2f(x); }

// 4x4 u32 redistribution within lane groups {lq, lq+16, lq+32, lq+48}:
// in : lane s holds bf16-pair at d = 16*j1 + 4*s + 2*j0 in reg v[2*j1+j0]
// out: lane g holds bf16-pair at d =  8*g + 2*p          in reg v[p]
// (converts swapped-MFMA C layout -> A/B fragment layout, in registers)
#if __has_builtin(__builtin_amdgcn_permlane32_swap) && __has_builtin(__builtin_amdgcn_permlane16_swap)
__device__ __forceinline__ void xpose4(u32& v0, u32& v1, u32& v2, u32& v3) {
  uv2 a = __builtin_amdgcn_permlane32_swap(v0, v2, false, false);
  uv2 b = __builtin_amdgcn_permlane32_swap(v1, v3, false, false);
  uv2 c = __builtin_amdgcn_permlane16_swap(a.x, a.y, false, false);
  uv2 d = __builtin_amdgcn_permlane16_swap(b.x, b.y, false, false);
  v0 = c.x; v2 = c.y; v1 = d.x; v3 = d.y;
}
#else
__device__ __forceinline__ void xpose4(u32& v0, u32& v1, u32& v2, u32& v3) {
  int lane = threadIdx.x & 63;
  { u32 t0 = __shfl_xor((int)v0, 32, 64), t2 = __shfl_xor((int)v2, 32, 64);
    bool lo = (lane & 32) == 0;
    u32 n0 = lo ? v0 : t2, n2 = lo ? t0 : v2; v0 = n0; v2 = n2; }
  { u32 t1 = __shfl_xor((int)v1, 32, 64), t3 = __shfl_xor((int)v3, 32, 64);
    bool lo = (lane & 32) == 0;
    u32 n1 = lo ? v1 : t3, n3 = lo ? t1 : v3; v1 = n1; v3 = n3; }
  { u32 t0 = __shfl_xor((int)v0, 16, 64), t2 = __shfl_xor((int)v2, 16, 64);
    bool lo = (lane & 16) == 0;
    u32 n0 = lo ? v0 : t2, n2 = lo ? t0 : v2; v0 = n0; v2 = n2; }
  { u32 t1 = __shfl_xor((int)v1, 16, 64), t3 = __shfl_xor((int)v3, 16, 64);
    bool lo = (lane & 16) == 0;
    u32 n1 = lo ? v1 : t3, n3 = lo ? t1 : v3; v1 = n1; v3 = n3; }
}
#endif

// exact-GELU via A&S 7.1.26 erf (|err| < 1.5e-7), branchless
__device__ __forceinline__ float gelu_f(float v) {
  float x = fabsf(v) * 0.70710678118654752f;
  float t = __builtin_amdgcn_rcpf(fmaf(x, 0.3275911f, 1.0f));
  float p = fmaf(t, 1.061405429f, -1.453152027f);
  p = fmaf(p, t, 1.421413741f);
  p = fmaf(p, t, -0.284496736f);
  p = fmaf(p, t, 0.254829592f);
  p = p * t;
  float e = ex2(v * v * -0.72134752044448170f);      // exp(-x^2), log2e folded
  float q = 0.5f * p * e;                            // Phi(-|x|)
  float phi = (v >= 0.0f) ? (1.0f - q) : q;
  return v * phi;
}

// LDS strides (u16 elements)
#define SH 104   // LN-out rows (96 used); 208B rows, bank-spread
#define SV 72    // V^T rows (64 used); 144B rows, 16B aligned

// ---- prepass: convert the 4 weight matrices to bf16 in workspace ----
__global__ void cvt_weights(const float* __restrict__ a, const float* __restrict__ b,
                            const float* __restrict__ c, const float* __restrict__ d,
                            u16* __restrict__ ws) {
  int i = blockIdx.x * 256 + threadIdx.x;
  if (i < 27648)       ws[i] = f2b(a[i]);
  else if (i < 36864)  ws[i] = f2b(b[i - 27648]);
  else if (i < 73728)  ws[i] = f2b(c[i - 36864]);
  else if (i < 110592) ws[i] = f2b(d[i - 73728]);
}

__global__ __launch_bounds__(256, 4)
void swin_mfma(const float* __restrict__ gx,
               const float* __restrict__ b_qkv,
               const float* __restrict__ b_out,
               const float* __restrict__ w_ln1, const float* __restrict__ b_ln1,
               const float* __restrict__ w_ln2, const float* __restrict__ b_ln2,
               const float* __restrict__ b_ff1, const float* __restrict__ b_ff2,
               const u16* __restrict__ ws,
               float* __restrict__ gout)
{
  // 13824 + 13312 + 256 = 27,392 B -> 4+ blocks/CU
  __shared__ __align__(16) u16 s_u[96 * SV];   // union: LN-out [64][SH] / V^T [96][SV]
  __shared__ __align__(16) u16 s_k[64 * SH];   // K rows (A-frag source)
  __shared__ __align__(16) int s_id[64];

  const int tid = threadIdx.x;
  const int w = tid >> 6, lane = tid & 63, g = lane >> 4, lq = lane & 15;
  const int blk = blockIdx.x, b = blk >> 6, wr = (blk >> 3) & 7, wc = blk & 7;

  const u16* wsq = ws;            // [288][96]
  const u16* wso = ws + 27648;    // [96][96]
  const u16* wf1 = ws + 36864;    // [384][96]
  const u16* wf2 = ws + 73728;    // [96][384]

  if (tid < 64) {
    int id = -1;
    if (tid < LD) {
      int i = tid / 7, j = tid - 7 * i;
      int rp = wr * 7 + i, cp = wc * 7 + j;
      int ri = (rp < 49) ? 0 : ((rp < 53) ? 1 : 2);
      int ci = (cp < 49) ? 0 : ((cp < 53) ? 1 : 2);
      id = ri * 3 + ci;
    }
    s_id[tid] = id;
  }

  // ---- x -> residual registers (C layout: resid[t][r] = x[16w+4g+r][16t+lq])
  float resid[6][4];
  size_t gbase[4];
#pragma unroll
  for (int r = 0; r < 4; ++r) {
    int token = 16 * w + 4 * g + r;
    int ti = token / 7, tj = token - 7 * ti;
    int row = wr * 7 + ti + 3; if (row >= FMAPD) row -= FMAPD;
    int col = wc * 7 + tj + 3; if (col >= FMAPD) col -= FMAPD;
    gbase[r] = ((size_t)b * (FMAPD * FMAPD) + row * FMAPD + col) * (size_t)CD + lq;
    bool val = token < LD;
#pragma unroll
    for (int t = 0; t < 6; ++t) {
      float v = gx[gbase[r] + 16 * t];
      resid[t][r] = val ? v : 0.f;
    }
  }

  // in-register LayerNorm -> bf16 rows (wave-private) into s_u (SH layout)
  auto layer_norm = [&](const float* lw, const float* lb) {
    float wv[6], bv[6];
#pragma unroll
    for (int t = 0; t < 6; ++t) { wv[t] = lw[16 * t + lq]; bv[t] = lb[16 * t + lq]; }
#pragma unroll
    for (int r = 0; r < 4; ++r) {
      float s = 0.f, s2 = 0.f;
#pragma unroll
      for (int t = 0; t < 6; ++t) { float v = resid[t][r]; s += v; s2 += v * v; }
#pragma unroll
      for (int m = 1; m <= 8; m <<= 1) { s += __shfl_xor(s, m, 64); s2 += __shfl_xor(s2, m, 64); }
      float mu = s * (1.f / 96.f);
      float rs = rsqrtf(s2 * (1.f / 96.f) - mu * mu + 1e-5f);
      u16* dst = s_u + (16 * w + 4 * g + r) * SH;
#pragma unroll
      for (int t = 0; t < 6; ++t) dst[16 * t + lq] = f2b((resid[t][r] - mu) * rs * wv[t] + bv[t]);
    }
  };
  layer_norm(w_ln1, b_ln1);

  bh8 af[3];
  {
    const u16* arow = s_u + (16 * w + lq) * SH;
#pragma unroll
    for (int kk = 0; kk < 3; ++kk) af[kk] = *(const bh8*)(arow + 32 * kk + 8 * g);
  }
  __syncthreads();   // B1: all af loaded; s_u region reusable as V^T

  // ---- QKV. Q stays in registers via xpose4; K -> s_k; V -> s_u (V^T).
  const float scaleL = 0.25505650948822f;   // (1/sqrt(32)) * log2(e)
  bh8 qa[3];
  {
#pragma unroll
    for (int c = 0; c < 3; ++c) {           // Q, 32-dim chunks
      u32 vv[4];
#pragma unroll
      for (int j1 = 0; j1 < 2; ++j1) {
        int t = 2 * c + j1;
        f4 acc = {0.f, 0.f, 0.f, 0.f};
#pragma unroll
        for (int kk = 0; kk < 3; ++kk) {
          bh8 bf = *(const bh8*)(wsq + (16 * t + lq) * CD + 32 * kk + 8 * g);
          acc = __builtin_amdgcn_mfma_f32_16x16x32_bf16(bf, af[kk], acc, 0, 0, 0);
        }
        float4 bq = *(const float4*)(b_qkv + 16 * t + 4 * g);
        vv[2 * j1 + 0] = pk2(fmaf(acc[0], scaleL, bq.x * scaleL),
                             fmaf(acc[1], scaleL, bq.y * scaleL));
        vv[2 * j1 + 1] = pk2(fmaf(acc[2], scaleL, bq.z * scaleL),
                             fmaf(acc[3], scaleL, bq.w * scaleL));
      }
      xpose4(vv[0], vv[1], vv[2], vv[3]);
      qa[c] = mk8(vv[0], vv[1], vv[2], vv[3]);
    }
#pragma unroll
    for (int t = 0; t < 6; ++t) {           // K (no bias: cancels in softmax)
      f4 acc = {0.f, 0.f, 0.f, 0.f};
#pragma unroll
      for (int kk = 0; kk < 3; ++kk) {
        bh8 bf = *(const bh8*)(wsq + (96 + 16 * t + lq) * CD + 32 * kk + 8 * g);
        acc = __builtin_amdgcn_mfma_f32_16x16x32_bf16(bf, af[kk], acc, 0, 0, 0);
      }
      uint2 u; u.x = pk2(acc[0], acc[1]); u.y = pk2(acc[2], acc[3]);
      *(uint2*)(s_k + (16 * w + lq) * SH + 16 * t + 4 * g) = u;
    }
#pragma unroll
    for (int t = 0; t < 6; ++t) {           // V -> V^T rows (overlay on s_u)
      f4 acc = {0.f, 0.f, 0.f, 0.f};
#pragma unroll
      for (int kk = 0; kk < 3; ++kk) {
        bh8 bf = *(const bh8*)(wsq + (192 + 16 * t + lq) * CD + 32 * kk + 8 * g);
        acc = __builtin_amdgcn_mfma_f32_16x16x32_bf16(af[kk], bf, acc, 0, 0, 0);
      }
      float bias = b_qkv[192 + 16 * t + lq];
      uint2 u; u.x = pk2(acc[0] + bias, acc[1] + bias);
      u.y = pk2(acc[2] + bias, acc[3] + bias);
      *(uint2*)(s_u + (16 * t + lq) * SV + 16 * w + 4 * g) = u;
    }
  }
  __syncthreads();   // B2: K / V^T / ids visible to all waves

  // ---- attention: mask as additive constant, exp2 softmax (max-skip safe here)
  float madd[4][4];
  {
    int id_i = s_id[16 * w + lq];
#pragma unroll
    for (int t = 0; t < 4; ++t) {
      int4 v = *(const int4*)(s_id + 16 * t + 4 * g);
      madd[t][0] = (v.x != id_i) ? -1.0e9f : 0.f;
      madd[t][1] = (v.y != id_i) ? -1.0e9f : 0.f;
      madd[t][2] = (v.z != id_i) ? -1.0e9f : 0.f;
      madd[t][3] = (v.w != id_i) ? -1.0e9f : 0.f;
    }
  }

  u32 oa[3][4];
#pragma unroll
  for (int hh = 0; hh < 3; ++hh) {
    f4 sc[4];
#pragma unroll
    for (int t = 0; t < 4; ++t) {
      bh8 kb = *(const bh8*)(s_k + (16 * t + lq) * SH + 32 * hh + 8 * g);
      f4 z = {0.f, 0.f, 0.f, 0.f};
      sc[t] = __builtin_amdgcn_mfma_f32_16x16x32_bf16(kb, qa[hh], z, 0, 0, 0);
    }
    float pv[4][4];
    float den = 0.f;
#pragma unroll
    for (int t = 0; t < 4; ++t)
#pragma unroll
      for (int r = 0; r < 4; ++r) {
        float e = ex2(sc[t][r] + madd[t][r]);   // Q pre-scaled by 1/sqrt(32)*log2e
        pv[t][r] = e; den += e;
      }
    den += __shfl_xor(den, 16, 64);
    den += __shfl_xor(den, 32, 64);
    float inv = __builtin_amdgcn_rcpf(den);
    bh8 pa[2];
#pragma unroll
    for (int c = 0; c < 2; ++c) {
      u32 vv[4];
      vv[0] = pk2(pv[2 * c][0] * inv, pv[2 * c][1] * inv);
      vv[1] = pk2(pv[2 * c][2] * inv, pv[2 * c][3] * inv);
      vv[2] = pk2(pv[2 * c + 1][0] * inv, pv[2 * c + 1][1] * inv);
      vv[3] = pk2(pv[2 * c + 1][2] * inv, pv[2 * c + 1][3] * inv);
      xpose4(vv[0], vv[1], vv[2], vv[3]);
      pa[c] = mk8(vv[0], vv[1], vv[2], vv[3]);
    }
    f4 o0 = {0.f, 0.f, 0.f, 0.f}, o1 = {0.f, 0.f, 0.f, 0.f};
    {
      const u16* vr0 = s_u + (32 * hh + lq) * SV;
      o0 = __builtin_amdgcn_mfma_f32_16x16x32_bf16(*(const bh8*)(vr0 + 8 * g), pa[0], o0, 0, 0, 0);
      o0 = __builtin_amdgcn_mfma_f32_16x16x32_bf16(*(const bh8*)(vr0 + 32 + 8 * g), pa[1], o0, 0, 0, 0);
      const u16* vr1 = s_u + (32 * hh + 16 + lq) * SV;
      o1 = __builtin_amdgcn_mfma_f32_16x16x32_bf16(*(const bh8*)(vr1 + 8 * g), pa[0], o1, 0, 0, 0);
      o1 = __builtin_amdgcn_mfma_f32_16x16x32_bf16(*(const bh8*)(vr1 + 32 + 8 * g), pa[1], o1, 0, 0, 0);
    }
    u32 vv[4];
    vv[0] = pk2(o0[0], o0[1]); vv[1] = pk2(o0[2], o0[3]);
    vv[2] = pk2(o1[0], o1[1]); vv[3] = pk2(o1[2], o1[3]);
    xpose4(vv[0], vv[1], vv[2], vv[3]);
    oa[hh][0] = vv[0]; oa[hh][1] = vv[1]; oa[hh][2] = vv[2]; oa[hh][3] = vv[3];
  }
  __syncthreads();   // B3: all PV reads of s_u done; s_u reusable for LN2

  // ---- out-projection: resid += o @ out_w^T + b (o already in A-frag regs)
  {
    bh8 oaf[3];
#pragma unroll
    for (int kk = 0; kk < 3; ++kk) oaf[kk] = mk8(oa[kk][0], oa[kk][1], oa[kk][2], oa[kk][3]);
#pragma unroll
    for (int t = 0; t < 6; ++t) {
      f4 acc = {0.f, 0.f, 0.f, 0.f};
#pragma unroll
      for (int kk = 0; kk < 3; ++kk) {
        bh8 bf = *(const bh8*)(wso + (16 * t + lq) * CD + 32 * kk + 8 * g);
        acc = __builtin_amdgcn_mfma_f32_16x16x32_bf16(oaf[kk], bf, acc, 0, 0, 0);
      }
      float bias = b_out[16 * t + lq];
#pragma unroll
      for (int r = 0; r < 4; ++r) resid[t][r] += acc[r] + bias;
    }
  }

  layer_norm(w_ln2, b_ln2);
  // fold FF2 bias into the trunk once
#pragma unroll
  for (int t = 0; t < 6; ++t) {
    float bb = b_ff2[16 * t + lq];
#pragma unroll
    for (int r = 0; r < 4; ++r) resid[t][r] += bb;
  }

  // ---- FFN, 4 quarters of 96; hidden stays in registers via xpose4
  {
    bh8 ha[3];
    const u16* hrow = s_u + (16 * w + lq) * SH;
#pragma unroll
    for (int kk = 0; kk < 3; ++kk) ha[kk] = *(const bh8*)(hrow + 32 * kk + 8 * g);
#pragma unroll 1
    for (int qq = 0; qq < 4; ++qq) {
      bh8 fa[3];
#pragma unroll
      for (int c = 0; c < 3; ++c) {
        u32 vv[4];
#pragma unroll
        for (int j1 = 0; j1 < 2; ++j1) {
          int t = 2 * c + j1;
          f4 acc = {0.f, 0.f, 0.f, 0.f};
#pragma unroll
          for (int kk = 0; kk < 3; ++kk) {
            bh8 bf = *(const bh8*)(wf1 + (96 * qq + 16 * t + lq) * CD + 32 * kk + 8 * g);
            acc = __builtin_amdgcn_mfma_f32_16x16x32_bf16(bf, ha[kk], acc, 0, 0, 0);
          }
          float4 bb = *(const float4*)(b_ff1 + 96 * qq + 16 * t + 4 * g);
          vv[2 * j1 + 0] = pk2(gelu_f(acc[0] + bb.x), gelu_f(acc[1] + bb.y));
          vv[2 * j1 + 1] = pk2(gelu_f(acc[2] + bb.z), gelu_f(acc[3] + bb.w));
        }
        xpose4(vv[0], vv[1], vv[2], vv[3]);
        fa[c] = mk8(vv[0], vv[1], vv[2], vv[3]);
      }
#pragma unroll
      for (int t = 0; t < 6; ++t) {
        f4 acc = {0.f, 0.f, 0.f, 0.f};
#pragma unroll
        for (int ks = 0; ks < 3; ++ks) {
          bh8 bf = *(const bh8*)(wf2 + (16 * t + lq) * 384 + 96 * qq + 32 * ks + 8 * g);
          acc = __builtin_amdgcn_mfma_f32_16x16x32_bf16(fa[ks], bf, acc, 0, 0, 0);
        }
#pragma unroll
        for (int r = 0; r < 4; ++r) resid[t][r] += acc[r];
      }
    }
  }

  // ---- store trunk (fp32), reverse window/shift mapping
#pragma unroll
  for (int r = 0; r < 4; ++r) {
    if (16 * w + 4 * g + r < LD) {
#pragma unroll
      for (int t = 0; t < 6; ++t) gout[gbase[r] + 16 * t] = resid[t][r];
    }
  }
}

extern "C" void kernel_launch(void* const* d_in, const int* in_sizes, int n_in,
                              void* d_out, int out_size, void* d_ws, size_t ws_size,
                              hipStream_t stream) {
  cvt_weights<<<432, 256, 0, stream>>>(
      (const float*)d_in[1], (const float*)d_in[3],
      (const float*)d_in[9], (const float*)d_in[11], (u16*)d_ws);
  swin_mfma<<<8192, 256, 0, stream>>>(
      (const float*)d_in[0],                          // x
      (const float*)d_in[2],                          // qkv_b
      (const float*)d_in[4],                          // out_b
      (const float*)d_in[5], (const float*)d_in[6],   // ln1
      (const float*)d_in[7], (const float*)d_in[8],   // ln2
      (const float*)d_in[10], (const float*)d_in[12], // ff1_b, ff2_b
      (const u16*)d_ws, (float*)d_out);
}

// Round 5
// 809.469 us; speedup vs baseline: 4.3687x; 1.0080x over previous
//
#include <hip/hip_runtime.h>
#include <hip/hip_bf16.h>
#include <stdint.h>

#define FMAPD 56
#define LD 49      // tokens per window
#define CD 96      // hidden

using u16 = unsigned short;
using u32 = unsigned int;

typedef __attribute__((ext_vector_type(8))) short bh8;   // 8 bf16 MFMA A/B frag
typedef __attribute__((ext_vector_type(4))) float f4;    // MFMA C/D frag
typedef __attribute__((ext_vector_type(2))) unsigned int uv2;

__device__ __forceinline__ u16 f2b(float f) {
  union { float f; u32 i; } v; v.f = f;
  u32 r = v.i + 0x7fffu + ((v.i >> 16) & 1u);   // RNE
  return (u16)(r >> 16);
}
// packed f32x2 -> bf16x2 via v_cvt_pk_bf16_f32 (RNE, single instruction)
__device__ __forceinline__ u32 pk2(float a, float b) {
  __hip_bfloat162 h = __float22bfloat162_rn(make_float2(a, b));
  union { __hip_bfloat162 v; u32 u; } c; c.v = h; return c.u;
}
__device__ __forceinline__ bh8 mk8(u32 a, u32 b, u32 c, u32 d) {
  union { u32 u[4]; bh8 v; } x;
  x.u[0] = a; x.u[1] = b; x.u[2] = c; x.u[3] = d;
  return x.v;
}
// 2^x via v_exp_f32 (exact hw exp2)
__device__ __forceinline__ float ex2(float x) { return __builtin_amdgcn_exp2f(x); }

// 4x4 u32 redistribution within lane groups {lq, lq+16, lq+32, lq+48}:
// converts swapped-MFMA C layout -> A/B fragment layout, in registers.
#if __has_builtin(__builtin_amdgcn_permlane32_swap) && __has_builtin(__builtin_amdgcn_permlane16_swap)
__device__ __forceinline__ void xpose4(u32& v0, u32& v1, u32& v2, u32& v3) {
  uv2 a = __builtin_amdgcn_permlane32_swap(v0, v2, false, false);
  uv2 b = __builtin_amdgcn_permlane32_swap(v1, v3, false, false);
  uv2 c = __builtin_amdgcn_permlane16_swap(a.x, a.y, false, false);
  uv2 d = __builtin_amdgcn_permlane16_swap(b.x, b.y, false, false);
  v0 = c.x; v2 = c.y; v1 = d.x; v3 = d.y;
}
#else
__device__ __forceinline__ void xpose4(u32& v0, u32& v1, u32& v2, u32& v3) {
  int lane = threadIdx.x & 63;
  { u32 t0 = __shfl_xor((int)v0, 32, 64), t2 = __shfl_xor((int)v2, 32, 64);
    bool lo = (lane & 32) == 0;
    u32 n0 = lo ? v0 : t2, n2 = lo ? t0 : v2; v0 = n0; v2 = n2; }
  { u32 t1 = __shfl_xor((int)v1, 32, 64), t3 = __shfl_xor((int)v3, 32, 64);
    bool lo = (lane & 32) == 0;
    u32 n1 = lo ? v1 : t3, n3 = lo ? t1 : v3; v1 = n1; v3 = n3; }
  { u32 t0 = __shfl_xor((int)v0, 16, 64), t2 = __shfl_xor((int)v2, 16, 64);
    bool lo = (lane & 16) == 0;
    u32 n0 = lo ? v0 : t2, n2 = lo ? t0 : v2; v0 = n0; v2 = n2; }
  { u32 t1 = __shfl_xor((int)v1, 16, 64), t3 = __shfl_xor((int)v3, 16, 64);
    bool lo = (lane & 16) == 0;
    u32 n1 = lo ? v1 : t3, n3 = lo ? t1 : v3; v1 = n1; v3 = n3; }
}
#endif

// tanh-form GELU: v * sigmoid(2*sqrt(2/pi)*(v + 0.044715 v^3))
// |err| vs exact erf-GELU ~7e-4 — far below bf16 quantization of the hidden.
__device__ __forceinline__ float gelu_f(float v) {
  float x2 = v * v;
  float t = fmaf(x2, -0.10294312f, -2.30220545f);   // -(c1 + c2*v^2), log2e folded
  float e = ex2(v * t);                              // exp2(-u)
  return v * __builtin_amdgcn_rcpf(1.0f + e);
}

// LDS strides (u16 elements)
#define SH 104   // LN-out rows (96 used); 208B rows, bank-spread
#define SV 72    // V^T rows (64 used); 144B rows, 16B aligned

// ---- prepass: convert the 4 weight matrices to bf16 in workspace ----
__global__ void cvt_weights(const float* __restrict__ a, const float* __restrict__ b,
                            const float* __restrict__ c, const float* __restrict__ d,
                            u16* __restrict__ ws) {
  int i = blockIdx.x * 256 + threadIdx.x;
  if (i < 27648)       ws[i] = f2b(a[i]);
  else if (i < 36864)  ws[i] = f2b(b[i - 27648]);
  else if (i < 73728)  ws[i] = f2b(c[i - 36864]);
  else if (i < 110592) ws[i] = f2b(d[i - 73728]);
}

__global__ __launch_bounds__(256, 4)
void swin_mfma(const float* __restrict__ gx,
               const float* __restrict__ b_qkv,
               const float* __restrict__ b_out,
               const float* __restrict__ w_ln1, const float* __restrict__ b_ln1,
               const float* __restrict__ w_ln2, const float* __restrict__ b_ln2,
               const float* __restrict__ b_ff1, const float* __restrict__ b_ff2,
               const u16* __restrict__ ws,
               float* __restrict__ gout)
{
  // 13824 + 13312 + 256 = 27,392 B -> 4 blocks/CU
  __shared__ __align__(16) u16 s_u[96 * SV];   // union: LN-out [64][SH] / V^T [96][SV]
  __shared__ __align__(16) u16 s_k[64 * SH];   // K rows (A-frag source)
  __shared__ __align__(16) int s_id[64];

  const int tid = threadIdx.x;
  const int w = tid >> 6, lane = tid & 63, g = lane >> 4, lq = lane & 15;
  const int blk = blockIdx.x, b = blk >> 6, wr = (blk >> 3) & 7, wc = blk & 7;

  const u16* wsq = ws;            // [288][96]
  const u16* wso = ws + 27648;    // [96][96]
  const u16* wf1 = ws + 36864;    // [384][96]
  const u16* wf2 = ws + 73728;    // [96][384]

  if (tid < 64) {
    int id = -1;
    if (tid < LD) {
      int i = tid / 7, j = tid - 7 * i;
      int rp = wr * 7 + i, cp = wc * 7 + j;
      int ri = (rp < 49) ? 0 : ((rp < 53) ? 1 : 2);
      int ci = (cp < 49) ? 0 : ((cp < 53) ? 1 : 2);
      id = ri * 3 + ci;
    }
    s_id[tid] = id;
  }

  // ---- x -> residual registers (C layout: resid[t][r] = x[16w+4g+r][16t+lq])
  float resid[6][4];
  size_t gbase[4];
#pragma unroll
  for (int r = 0; r < 4; ++r) {
    int token = 16 * w + 4 * g + r;
    int ti = token / 7, tj = token - 7 * ti;
    int row = wr * 7 + ti + 3; if (row >= FMAPD) row -= FMAPD;
    int col = wc * 7 + tj + 3; if (col >= FMAPD) col -= FMAPD;
    gbase[r] = ((size_t)b * (FMAPD * FMAPD) + row * FMAPD + col) * (size_t)CD + lq;
    bool val = token < LD;
#pragma unroll
    for (int t = 0; t < 6; ++t) {
      float v = gx[gbase[r] + 16 * t];
      resid[t][r] = val ? v : 0.f;
    }
  }

  // in-register LayerNorm -> bf16 rows (wave-private) into s_u (SH layout)
  auto layer_norm = [&](const float* lw, const float* lb) {
    float wv[6], bv[6];
#pragma unroll
    for (int t = 0; t < 6; ++t) { wv[t] = lw[16 * t + lq]; bv[t] = lb[16 * t + lq]; }
#pragma unroll
    for (int r = 0; r < 4; ++r) {
      float s = 0.f, s2 = 0.f;
#pragma unroll
      for (int t = 0; t < 6; ++t) { float v = resid[t][r]; s += v; s2 += v * v; }
#pragma unroll
      for (int m = 1; m <= 8; m <<= 1) { s += __shfl_xor(s, m, 64); s2 += __shfl_xor(s2, m, 64); }
      float mu = s * (1.f / 96.f);
      float rs = rsqrtf(s2 * (1.f / 96.f) - mu * mu + 1e-5f);
      u16* dst = s_u + (16 * w + 4 * g + r) * SH;
#pragma unroll
      for (int t = 0; t < 6; ++t) dst[16 * t + lq] = f2b((resid[t][r] - mu) * rs * wv[t] + bv[t]);
    }
  };
  layer_norm(w_ln1, b_ln1);

  bh8 af[3];
  {
    const u16* arow = s_u + (16 * w + lq) * SH;
#pragma unroll
    for (int kk = 0; kk < 3; ++kk) af[kk] = *(const bh8*)(arow + 32 * kk + 8 * g);
  }
  __syncthreads();   // B1: all af loaded; s_u region reusable as V^T

  // ---- QKV. Q stays in registers via xpose4; K -> s_k; V -> s_u (V^T).
  const float scaleL = 0.25505650948822f;   // (1/sqrt(32)) * log2(e)
  bh8 qa[3];
  {
#pragma unroll
    for (int c = 0; c < 3; ++c) {           // Q, 32-dim chunks
      u32 vv[4];
#pragma unroll
      for (int j1 = 0; j1 < 2; ++j1) {
        int t = 2 * c + j1;
        f4 acc = {0.f, 0.f, 0.f, 0.f};
#pragma unroll
        for (int kk = 0; kk < 3; ++kk) {
          bh8 bf = *(const bh8*)(wsq + (16 * t + lq) * CD + 32 * kk + 8 * g);
          acc = __builtin_amdgcn_mfma_f32_16x16x32_bf16(bf, af[kk], acc, 0, 0, 0);
        }
        float4 bq = *(const float4*)(b_qkv + 16 * t + 4 * g);
        vv[2 * j1 + 0] = pk2(fmaf(acc[0], scaleL, bq.x * scaleL),
                             fmaf(acc[1], scaleL, bq.y * scaleL));
        vv[2 * j1 + 1] = pk2(fmaf(acc[2], scaleL, bq.z * scaleL),
                             fmaf(acc[3], scaleL, bq.w * scaleL));
      }
      xpose4(vv[0], vv[1], vv[2], vv[3]);
      qa[c] = mk8(vv[0], vv[1], vv[2], vv[3]);
    }
#pragma unroll
    for (int t = 0; t < 6; ++t) {           // K (no bias: cancels in softmax)
      f4 acc = {0.f, 0.f, 0.f, 0.f};
#pragma unroll
      for (int kk = 0; kk < 3; ++kk) {
        bh8 bf = *(const bh8*)(wsq + (96 + 16 * t + lq) * CD + 32 * kk + 8 * g);
        acc = __builtin_amdgcn_mfma_f32_16x16x32_bf16(bf, af[kk], acc, 0, 0, 0);
      }
      uint2 u; u.x = pk2(acc[0], acc[1]); u.y = pk2(acc[2], acc[3]);
      *(uint2*)(s_k + (16 * w + lq) * SH + 16 * t + 4 * g) = u;
    }
#pragma unroll
    for (int t = 0; t < 6; ++t) {           // V -> V^T rows (overlay on s_u)
      f4 acc = {0.f, 0.f, 0.f, 0.f};
#pragma unroll
      for (int kk = 0; kk < 3; ++kk) {
        bh8 bf = *(const bh8*)(wsq + (192 + 16 * t + lq) * CD + 32 * kk + 8 * g);
        acc = __builtin_amdgcn_mfma_f32_16x16x32_bf16(af[kk], bf, acc, 0, 0, 0);
      }
      float bias = b_qkv[192 + 16 * t + lq];
      uint2 u; u.x = pk2(acc[0] + bias, acc[1] + bias);
      u.y = pk2(acc[2] + bias, acc[3] + bias);
      *(uint2*)(s_u + (16 * t + lq) * SV + 16 * w + 4 * g) = u;
    }
  }
  __syncthreads();   // B2: K / V^T / ids visible to all waves

  // ---- attention: mask as additive constant, exp2 softmax (max-skip safe:
  // LN-bounded scores; masked lanes -> exp2(-1e9)=0; padding rows self-match)
  float madd[4][4];
  {
    int id_i = s_id[16 * w + lq];
#pragma unroll
    for (int t = 0; t < 4; ++t) {
      int4 v = *(const int4*)(s_id + 16 * t + 4 * g);
      madd[t][0] = (v.x != id_i) ? -1.0e9f : 0.f;
      madd[t][1] = (v.y != id_i) ? -1.0e9f : 0.f;
      madd[t][2] = (v.z != id_i) ? -1.0e9f : 0.f;
      madd[t][3] = (v.w != id_i) ? -1.0e9f : 0.f;
    }
  }

  u32 oa[3][4];
#pragma unroll
  for (int hh = 0; hh < 3; ++hh) {
    f4 sc[4];
#pragma unroll
    for (int t = 0; t < 4; ++t) {
      bh8 kb = *(const bh8*)(s_k + (16 * t + lq) * SH + 32 * hh + 8 * g);
      f4 z = {0.f, 0.f, 0.f, 0.f};
      sc[t] = __builtin_amdgcn_mfma_f32_16x16x32_bf16(kb, qa[hh], z, 0, 0, 0);
    }
    // unnormalized P: e = exp2(s + mask); den accumulated, applied to o later
    float pv[4][4];
    float den = 0.f;
#pragma unroll
    for (int t = 0; t < 4; ++t)
#pragma unroll
      for (int r = 0; r < 4; ++r) {
        float e = ex2(sc[t][r] + madd[t][r]);   // Q pre-scaled by 1/sqrt(32)*log2e
        pv[t][r] = e; den += e;
      }
    bh8 pa[2];
#pragma unroll
    for (int c = 0; c < 2; ++c) {
      u32 vv[4];
      vv[0] = pk2(pv[2 * c][0], pv[2 * c][1]);
      vv[1] = pk2(pv[2 * c][2], pv[2 * c][3]);
      vv[2] = pk2(pv[2 * c + 1][0], pv[2 * c + 1][1]);
      vv[3] = pk2(pv[2 * c + 1][2], pv[2 * c + 1][3]);
      xpose4(vv[0], vv[1], vv[2], vv[3]);
      pa[c] = mk8(vv[0], vv[1], vv[2], vv[3]);
    }
    f4 o0 = {0.f, 0.f, 0.f, 0.f}, o1 = {0.f, 0.f, 0.f, 0.f};
    {
      const u16* vr0 = s_u + (32 * hh + lq) * SV;
      o0 = __builtin_amdgcn_mfma_f32_16x16x32_bf16(*(const bh8*)(vr0 + 8 * g), pa[0], o0, 0, 0, 0);
      o0 = __builtin_amdgcn_mfma_f32_16x16x32_bf16(*(const bh8*)(vr0 + 32 + 8 * g), pa[1], o0, 0, 0, 0);
      const u16* vr1 = s_u + (32 * hh + 16 + lq) * SV;
      o1 = __builtin_amdgcn_mfma_f32_16x16x32_bf16(*(const bh8*)(vr1 + 8 * g), pa[0], o1, 0, 0, 0);
      o1 = __builtin_amdgcn_mfma_f32_16x16x32_bf16(*(const bh8*)(vr1 + 32 + 8 * g), pa[1], o1, 0, 0, 0);
    }
    // row-sum across the 4 lane groups, then fold 1/den into the o pack
    den += __shfl_xor(den, 16, 64);
    den += __shfl_xor(den, 32, 64);
    float inv = __builtin_amdgcn_rcpf(den);
    u32 vv[4];
    vv[0] = pk2(o0[0] * inv, o0[1] * inv); vv[1] = pk2(o0[2] * inv, o0[3] * inv);
    vv[2] = pk2(o1[0] * inv, o1[1] * inv); vv[3] = pk2(o1[2] * inv, o1[3] * inv);
    xpose4(vv[0], vv[1], vv[2], vv[3]);
    oa[hh][0] = vv[0]; oa[hh][1] = vv[1]; oa[hh][2] = vv[2]; oa[hh][3] = vv[3];
  }
  __syncthreads();   // B3: all PV reads of s_u done; s_u reusable for LN2

  // ---- out-projection: resid += o @ out_w^T + b (o already in A-frag regs)
  {
    bh8 oaf[3];
#pragma unroll
    for (int kk = 0; kk < 3; ++kk) oaf[kk] = mk8(oa[kk][0], oa[kk][1], oa[kk][2], oa[kk][3]);
#pragma unroll
    for (int t = 0; t < 6; ++t) {
      f4 acc = {0.f, 0.f, 0.f, 0.f};
#pragma unroll
      for (int kk = 0; kk < 3; ++kk) {
        bh8 bf = *(const bh8*)(wso + (16 * t + lq) * CD + 32 * kk + 8 * g);
        acc = __builtin_amdgcn_mfma_f32_16x16x32_bf16(oaf[kk], bf, acc, 0, 0, 0);
      }
      float bias = b_out[16 * t + lq];
#pragma unroll
      for (int r = 0; r < 4; ++r) resid[t][r] += acc[r] + bias;
    }
  }

  layer_norm(w_ln2, b_ln2);
  // fold FF2 bias into the trunk once
#pragma unroll
  for (int t = 0; t < 6; ++t) {
    float bb = b_ff2[16 * t + lq];
#pragma unroll
    for (int r = 0; r < 4; ++r) resid[t][r] += bb;
  }

  // ---- FFN, 4 quarters of 96; hidden stays in registers via xpose4
  {
    bh8 ha[3];
    const u16* hrow = s_u + (16 * w + lq) * SH;
#pragma unroll
    for (int kk = 0; kk < 3; ++kk) ha[kk] = *(const bh8*)(hrow + 32 * kk + 8 * g);
#pragma unroll 1
    for (int qq = 0; qq < 4; ++qq) {
      bh8 fa[3];
#pragma unroll
      for (int c = 0; c < 3; ++c) {
        u32 vv[4];
#pragma unroll
        for (int j1 = 0; j1 < 2; ++j1) {
          int t = 2 * c + j1;
          f4 acc = {0.f, 0.f, 0.f, 0.f};
#pragma unroll
          for (int kk = 0; kk < 3; ++kk) {
            bh8 bf = *(const bh8*)(wf1 + (96 * qq + 16 * t + lq) * CD + 32 * kk + 8 * g);
            acc = __builtin_amdgcn_mfma_f32_16x16x32_bf16(bf, ha[kk], acc, 0, 0, 0);
          }
          float4 bb = *(const float4*)(b_ff1 + 96 * qq + 16 * t + 4 * g);
          vv[2 * j1 + 0] = pk2(gelu_f(acc[0] + bb.x), gelu_f(acc[1] + bb.y));
          vv[2 * j1 + 1] = pk2(gelu_f(acc[2] + bb.z), gelu_f(acc[3] + bb.w));
        }
        xpose4(vv[0], vv[1], vv[2], vv[3]);
        fa[c] = mk8(vv[0], vv[1], vv[2], vv[3]);
      }
#pragma unroll
      for (int t = 0; t < 6; ++t) {
        f4 acc = {0.f, 0.f, 0.f, 0.f};
#pragma unroll
        for (int ks = 0; ks < 3; ++ks) {
          bh8 bf = *(const bh8*)(wf2 + (16 * t + lq) * 384 + 96 * qq + 32 * ks + 8 * g);
          acc = __builtin_amdgcn_mfma_f32_16x16x32_bf16(fa[ks], bf, acc, 0, 0, 0);
        }
#pragma unroll
        for (int r = 0; r < 4; ++r) resid[t][r] += acc[r];
      }
    }
  }

  // ---- store trunk (fp32), reverse window/shift mapping
#pragma unroll
  for (int r = 0; r < 4; ++r) {
    if (16 * w + 4 * g + r < LD) {
#pragma unroll
      for (int t = 0; t < 6; ++t) gout[gbase[r] + 16 * t] = resid[t][r];
    }
  }
}

extern "C" void kernel_launch(void* const* d_in, const int* in_sizes, int n_in,
                              void* d_out, int out_size, void* d_ws, size_t ws_size,
                              hipStream_t stream) {
  cvt_weights<<<432, 256, 0, stream>>>(
      (const float*)d_in[1], (const float*)d_in[3],
      (const float*)d_in[9], (const float*)d_in[11], (u16*)d_ws);
  swin_mfma<<<8192, 256, 0, stream>>>(
      (const float*)d_in[0],                          // x
      (const float*)d_in[2],                          // qkv_b
      (const float*)d_in[4],                          // out_b
      (const float*)d_in[5], (const float*)d_in[6],   // ln1
      (const float*)d_in[7], (const float*)d_in[8],   // ln2
      (const float*)d_in[10], (const float*)d_in[12], // ff1_b, ff2_b
      (const u16*)d_ws, (float*)d_out);
}

// Round 7
// 805.437 us; speedup vs baseline: 4.3905x; 1.0050x over previous
//
#include <hip/hip_runtime.h>
#include <hip/hip_bf16.h>
#include <stdint.h>

#define FMAPD 56
#define LD 49      // tokens per window
#define CD 96      // hidden

using u16 = unsigned short;
using u32 = unsigned int;

typedef __attribute__((ext_vector_type(8))) short bh8;   // 8 bf16 MFMA A/B frag
typedef __attribute__((ext_vector_type(4))) float f4;    // MFMA C/D frag
typedef __attribute__((ext_vector_type(2))) unsigned int uv2;

__device__ __forceinline__ u16 f2b(float f) {
  union { float f; u32 i; } v; v.f = f;
  u32 r = v.i + 0x7fffu + ((v.i >> 16) & 1u);   // RNE
  return (u16)(r >> 16);
}
// packed f32x2 -> bf16x2 via v_cvt_pk_bf16_f32 (RNE, single instruction)
__device__ __forceinline__ u32 pk2(float a, float b) {
  __hip_bfloat162 h = __float22bfloat162_rn(make_float2(a, b));
  union { __hip_bfloat162 v; u32 u; } c; c.v = h; return c.u;
}
__device__ __forceinline__ bh8 mk8(u32 a, u32 b, u32 c, u32 d) {
  union { u32 u[4]; bh8 v; } x;
  x.u[0] = a; x.u[1] = b; x.u[2] = c; x.u[3] = d;
  return x.v;
}
// 2^x via v_exp_f32 (exact hw exp2)
__device__ __forceinline__ float ex2(float x) { return __builtin_amdgcn_exp2f(x); }

// intra-16-lane (DPP row) sum reduction, result broadcast to all 16 lanes.
// VALU-only (v_add with DPP row_ror) — replaces ds_swizzle shfl chains.
// CTRL must be a compile-time constant -> template parameter.
template <int CTRL>
__device__ __forceinline__ float dpp_radd(float x) {
  int y = __builtin_amdgcn_update_dpp(0, __float_as_int(x), CTRL, 0xf, 0xf, true);
  return x + __int_as_float(y);
}
__device__ __forceinline__ float rowsum16(float x) {
  x = dpp_radd<0x128>(x);   // row_ror:8
  x = dpp_radd<0x124>(x);   // row_ror:4
  x = dpp_radd<0x122>(x);   // row_ror:2
  x = dpp_radd<0x121>(x);   // row_ror:1
  return x;
}

// 4x4 u32 redistribution within lane groups {lq, lq+16, lq+32, lq+48}:
// converts swapped-MFMA C layout -> A/B fragment layout, in registers.
#if __has_builtin(__builtin_amdgcn_permlane32_swap) && __has_builtin(__builtin_amdgcn_permlane16_swap)
__device__ __forceinline__ void xpose4(u32& v0, u32& v1, u32& v2, u32& v3) {
  uv2 a = __builtin_amdgcn_permlane32_swap(v0, v2, false, false);
  uv2 b = __builtin_amdgcn_permlane32_swap(v1, v3, false, false);
  uv2 c = __builtin_amdgcn_permlane16_swap(a.x, a.y, false, false);
  uv2 d = __builtin_amdgcn_permlane16_swap(b.x, b.y, false, false);
  v0 = c.x; v2 = c.y; v1 = d.x; v3 = d.y;
}
#else
__device__ __forceinline__ void xpose4(u32& v0, u32& v1, u32& v2, u32& v3) {
  int lane = threadIdx.x & 63;
  { u32 t0 = __shfl_xor((int)v0, 32, 64), t2 = __shfl_xor((int)v2, 32, 64);
    bool lo = (lane & 32) == 0;
    u32 n0 = lo ? v0 : t2, n2 = lo ? t0 : v2; v0 = n0; v2 = n2; }
  { u32 t1 = __shfl_xor((int)v1, 32, 64), t3 = __shfl_xor((int)v3, 32, 64);
    bool lo = (lane & 32) == 0;
    u32 n1 = lo ? v1 : t3, n3 = lo ? t1 : v3; v1 = n1; v3 = n3; }
  { u32 t0 = __shfl_xor((int)v0, 16, 64), t2 = __shfl_xor((int)v2, 16, 64);
    bool lo = (lane & 16) == 0;
    u32 n0 = lo ? v0 : t2, n2 = lo ? t0 : v2; v0 = n0; v2 = n2; }
  { u32 t1 = __shfl_xor((int)v1, 16, 64), t3 = __shfl_xor((int)v3, 16, 64);
    bool lo = (lane & 16) == 0;
    u32 n1 = lo ? v1 : t3, n3 = lo ? t1 : v3; v1 = n1; v3 = n3; }
}
#endif

// tanh-form GELU: v * sigmoid(2*sqrt(2/pi)*(v + 0.044715 v^3))
__device__ __forceinline__ float gelu_f(float v) {
  float x2 = v * v;
  float t = fmaf(x2, -0.10294312f, -2.30220545f);   // -(c1 + c2*v^2), log2e folded
  float e = ex2(v * t);
  return v * __builtin_amdgcn_rcpf(1.0f + e);
}

// LDS strides (u16 elements)
#define SH 104   // LN-out rows (96 used); wave-private staging
#define SV 68    // V^T rows (64 used); 136B rows (8B aligned)

// ---- prepass: convert the 4 weight matrices to bf16 in workspace ----
__global__ void cvt_weights(const float* __restrict__ a, const float* __restrict__ b,
                            const float* __restrict__ c, const float* __restrict__ d,
                            u16* __restrict__ ws) {
  int i = blockIdx.x * 256 + threadIdx.x;
  if (i < 27648)       ws[i] = f2b(a[i]);
  else if (i < 36864)  ws[i] = f2b(b[i - 27648]);
  else if (i < 73728)  ws[i] = f2b(c[i - 36864]);
  else if (i < 110592) ws[i] = f2b(d[i - 73728]);
}

__global__ __launch_bounds__(256, 4)
void swin_mfma(const float* __restrict__ gx,
               const float* __restrict__ b_qkv,
               const float* __restrict__ b_out,
               const float* __restrict__ w_ln1, const float* __restrict__ b_ln1,
               const float* __restrict__ w_ln2, const float* __restrict__ b_ln2,
               const float* __restrict__ b_ff1, const float* __restrict__ b_ff2,
               const u16* __restrict__ ws,
               float* __restrict__ gout)
{
  // 13312 + 13312 + 13056 + 256 = 39,936 B -> 4 blocks/CU (40,960 budget)
  __shared__ __align__(16) u16 s_u[64 * SH];   // LN staging, wave-private rows
  __shared__ __align__(16) u16 s_k[64 * SH];   // K rows (cross-wave)
  __shared__ __align__(16) u16 s_v[96 * SV];   // V^T rows (cross-wave)
  __shared__ __align__(16) int s_id[64];

  const int tid = threadIdx.x;
  const int w = tid >> 6, lane = tid & 63, g = lane >> 4, lq = lane & 15;
  const int blk = blockIdx.x, b = blk >> 6, wr = (blk >> 3) & 7, wc = blk & 7;

  const u16* wsq = ws;            // [288][96]
  const u16* wso = ws + 27648;    // [96][96]
  const u16* wf1 = ws + 36864;    // [384][96]
  const u16* wf2 = ws + 73728;    // [96][384]

  if (tid < 64) {
    int id = -1;
    if (tid < LD) {
      int i = tid / 7, j = tid - 7 * i;
      int rp = wr * 7 + i, cp = wc * 7 + j;
      int ri = (rp < 49) ? 0 : ((rp < 53) ? 1 : 2);
      int ci = (cp < 49) ? 0 : ((cp < 53) ? 1 : 2);
      id = ri * 3 + ci;
    }
    s_id[tid] = id;
  }

  // ---- x -> residual registers (C layout: resid[t][r] = x[16w+4g+r][16t+lq])
  float resid[6][4];
  size_t gbase[4];
#pragma unroll
  for (int r = 0; r < 4; ++r) {
    int token = 16 * w + 4 * g + r;
    int ti = token / 7, tj = token - 7 * ti;
    int row = wr * 7 + ti + 3; if (row >= FMAPD) row -= FMAPD;
    int col = wc * 7 + tj + 3; if (col >= FMAPD) col -= FMAPD;
    gbase[r] = ((size_t)b * (FMAPD * FMAPD) + row * FMAPD + col) * (size_t)CD + lq;
    bool val = token < LD;
#pragma unroll
    for (int t = 0; t < 6; ++t) {
      float v = gx[gbase[r] + 16 * t];
      resid[t][r] = val ? v : 0.f;
    }
  }

  // in-register LayerNorm -> bf16 rows (wave-private) into s_u
  // row stats via DPP row_ror adds (VALU) instead of ds-pipe shuffles
  auto layer_norm = [&](const float* lw, const float* lb) {
    float wv[6], bv[6];
#pragma unroll
    for (int t = 0; t < 6; ++t) { wv[t] = lw[16 * t + lq]; bv[t] = lb[16 * t + lq]; }
#pragma unroll
    for (int r = 0; r < 4; ++r) {
      float s = 0.f, s2 = 0.f;
#pragma unroll
      for (int t = 0; t < 6; ++t) { float v = resid[t][r]; s += v; s2 += v * v; }
      s = rowsum16(s);
      s2 = rowsum16(s2);
      float mu = s * (1.f / 96.f);
      float rs = rsqrtf(s2 * (1.f / 96.f) - mu * mu + 1e-5f);
      u16* dst = s_u + (16 * w + 4 * g + r) * SH;
#pragma unroll
      for (int t = 0; t < 6; ++t) dst[16 * t + lq] = f2b((resid[t][r] - mu) * rs * wv[t] + bv[t]);
    }
  };
  layer_norm(w_ln1, b_ln1);

  bh8 af[3];
  {
    const u16* arow = s_u + (16 * w + lq) * SH;   // same-wave rows; lgkmcnt-ordered
#pragma unroll
    for (int kk = 0; kk < 3; ++kk) af[kk] = *(const bh8*)(arow + 32 * kk + 8 * g);
  }

  // ---- QKV. Q stays in registers via xpose4; K -> s_k; V -> s_v (V^T).
  const float scaleL = 0.25505650948822f;   // (1/sqrt(32)) * log2(e)
  bh8 qa[3];
  {
#pragma unroll
    for (int c = 0; c < 3; ++c) {           // Q, 32-dim chunks
      u32 vv[4];
#pragma unroll
      for (int j1 = 0; j1 < 2; ++j1) {
        int t = 2 * c + j1;
        f4 acc = {0.f, 0.f, 0.f, 0.f};
#pragma unroll
        for (int kk = 0; kk < 3; ++kk) {
          bh8 bf = *(const bh8*)(wsq + (16 * t + lq) * CD + 32 * kk + 8 * g);
          acc = __builtin_amdgcn_mfma_f32_16x16x32_bf16(bf, af[kk], acc, 0, 0, 0);
        }
        float4 bq = *(const float4*)(b_qkv + 16 * t + 4 * g);
        vv[2 * j1 + 0] = pk2(fmaf(acc[0], scaleL, bq.x * scaleL),
                             fmaf(acc[1], scaleL, bq.y * scaleL));
        vv[2 * j1 + 1] = pk2(fmaf(acc[2], scaleL, bq.z * scaleL),
                             fmaf(acc[3], scaleL, bq.w * scaleL));
      }
      xpose4(vv[0], vv[1], vv[2], vv[3]);
      qa[c] = mk8(vv[0], vv[1], vv[2], vv[3]);
    }
#pragma unroll
    for (int t = 0; t < 6; ++t) {           // K (no bias: cancels in softmax)
      f4 acc = {0.f, 0.f, 0.f, 0.f};
#pragma unroll
      for (int kk = 0; kk < 3; ++kk) {
        bh8 bf = *(const bh8*)(wsq + (96 + 16 * t + lq) * CD + 32 * kk + 8 * g);
        acc = __builtin_amdgcn_mfma_f32_16x16x32_bf16(bf, af[kk], acc, 0, 0, 0);
      }
      uint2 u; u.x = pk2(acc[0], acc[1]); u.y = pk2(acc[2], acc[3]);
      *(uint2*)(s_k + (16 * w + lq) * SH + 16 * t + 4 * g) = u;
    }
#pragma unroll
    for (int t = 0; t < 6; ++t) {           // V -> V^T rows (dedicated s_v)
      f4 acc = {0.f, 0.f, 0.f, 0.f};
#pragma unroll
      for (int kk = 0; kk < 3; ++kk) {
        bh8 bf = *(const bh8*)(wsq + (192 + 16 * t + lq) * CD + 32 * kk + 8 * g);
        acc = __builtin_amdgcn_mfma_f32_16x16x32_bf16(af[kk], bf, acc, 0, 0, 0);
      }
      float bias = b_qkv[192 + 16 * t + lq];
      uint2 u; u.x = pk2(acc[0] + bias, acc[1] + bias);
      u.y = pk2(acc[2] + bias, acc[3] + bias);
      *(uint2*)(s_v + (16 * t + lq) * SV + 16 * w + 4 * g) = u;
    }
  }
  __syncthreads();   // the ONLY barrier: K / V^T / ids published to all waves

  // ---- attention: mask as additive constant, exp2 softmax (max-skip safe:
  // LN-bounded scores; masked lanes -> exp2(-1e9)=0; padding rows self-match)
  float madd[4][4];
  {
    int id_i = s_id[16 * w + lq];
#pragma unroll
    for (int t = 0; t < 4; ++t) {
      int4 v = *(const int4*)(s_id + 16 * t + 4 * g);
      madd[t][0] = (v.x != id_i) ? -1.0e9f : 0.f;
      madd[t][1] = (v.y != id_i) ? -1.0e9f : 0.f;
      madd[t][2] = (v.z != id_i) ? -1.0e9f : 0.f;
      madd[t][3] = (v.w != id_i) ? -1.0e9f : 0.f;
    }
  }

  u32 oa[3][4];
#pragma unroll
  for (int hh = 0; hh < 3; ++hh) {
    f4 sc[4];
#pragma unroll
    for (int t = 0; t < 4; ++t) {
      bh8 kb = *(const bh8*)(s_k + (16 * t + lq) * SH + 32 * hh + 8 * g);
      f4 z = {0.f, 0.f, 0.f, 0.f};
      sc[t] = __builtin_amdgcn_mfma_f32_16x16x32_bf16(kb, qa[hh], z, 0, 0, 0);
    }
    // unnormalized P: e = exp2(s + mask); den applied to o after PV
    float pv[4][4];
    float den = 0.f;
#pragma unroll
    for (int t = 0; t < 4; ++t)
#pragma unroll
      for (int r = 0; r < 4; ++r) {
        float e = ex2(sc[t][r] + madd[t][r]);
        pv[t][r] = e; den += e;
      }
    bh8 pa[2];
#pragma unroll
    for (int c = 0; c < 2; ++c) {
      u32 vv[4];
      vv[0] = pk2(pv[2 * c][0], pv[2 * c][1]);
      vv[1] = pk2(pv[2 * c][2], pv[2 * c][3]);
      vv[2] = pk2(pv[2 * c + 1][0], pv[2 * c + 1][1]);
      vv[3] = pk2(pv[2 * c + 1][2], pv[2 * c + 1][3]);
      xpose4(vv[0], vv[1], vv[2], vv[3]);
      pa[c] = mk8(vv[0], vv[1], vv[2], vv[3]);
    }
    f4 o0 = {0.f, 0.f, 0.f, 0.f}, o1 = {0.f, 0.f, 0.f, 0.f};
    {
      const u16* vr0 = s_v + (32 * hh + lq) * SV;
      o0 = __builtin_amdgcn_mfma_f32_16x16x32_bf16(*(const bh8*)(vr0 + 8 * g), pa[0], o0, 0, 0, 0);
      o0 = __builtin_amdgcn_mfma_f32_16x16x32_bf16(*(const bh8*)(vr0 + 32 + 8 * g), pa[1], o0, 0, 0, 0);
      const u16* vr1 = s_v + (32 * hh + 16 + lq) * SV;
      o1 = __builtin_amdgcn_mfma_f32_16x16x32_bf16(*(const bh8*)(vr1 + 8 * g), pa[0], o1, 0, 0, 0);
      o1 = __builtin_amdgcn_mfma_f32_16x16x32_bf16(*(const bh8*)(vr1 + 32 + 8 * g), pa[1], o1, 0, 0, 0);
    }
    // row-sum across the 4 lane groups, then fold 1/den into the o pack
    den += __shfl_xor(den, 16, 64);
    den += __shfl_xor(den, 32, 64);
    float inv = __builtin_amdgcn_rcpf(den);
    u32 vv[4];
    vv[0] = pk2(o0[0] * inv, o0[1] * inv); vv[1] = pk2(o0[2] * inv, o0[3] * inv);
    vv[2] = pk2(o1[0] * inv, o1[1] * inv); vv[3] = pk2(o1[2] * inv, o1[3] * inv);
    xpose4(vv[0], vv[1], vv[2], vv[3]);
    oa[hh][0] = vv[0]; oa[hh][1] = vv[1]; oa[hh][2] = vv[2]; oa[hh][3] = vv[3];
  }

  // ---- out-projection: resid += o @ out_w^T + b (o already in A-frag regs)
  {
    bh8 oaf[3];
#pragma unroll
    for (int kk = 0; kk < 3; ++kk) oaf[kk] = mk8(oa[kk][0], oa[kk][1], oa[kk][2], oa[kk][3]);
#pragma unroll
    for (int t = 0; t < 6; ++t) {
      f4 acc = {0.f, 0.f, 0.f, 0.f};
#pragma unroll
      for (int kk = 0; kk < 3; ++kk) {
        bh8 bf = *(const bh8*)(wso + (16 * t + lq) * CD + 32 * kk + 8 * g);
        acc = __builtin_amdgcn_mfma_f32_16x16x32_bf16(oaf[kk], bf, acc, 0, 0, 0);
      }
      float bias = b_out[16 * t + lq];
#pragma unroll
      for (int r = 0; r < 4; ++r) resid[t][r] += acc[r] + bias;
    }
  }

  layer_norm(w_ln2, b_ln2);   // writes s_u own-wave rows (wave-private; no barrier)
  // fold FF2 bias into the trunk once
#pragma unroll
  for (int t = 0; t < 6; ++t) {
    float bb = b_ff2[16 * t + lq];
#pragma unroll
    for (int r = 0; r < 4; ++r) resid[t][r] += bb;
  }

  // ---- FFN, 4 quarters of 96; hidden stays in registers via xpose4
  {
    bh8 ha[3];
    const u16* hrow = s_u + (16 * w + lq) * SH;
#pragma unroll
    for (int kk = 0; kk < 3; ++kk) ha[kk] = *(const bh8*)(hrow + 32 * kk + 8 * g);
#pragma unroll 1
    for (int qq = 0; qq < 4; ++qq) {
      bh8 fa[3];
#pragma unroll
      for (int c = 0; c < 3; ++c) {
        u32 vv[4];
#pragma unroll
        for (int j1 = 0; j1 < 2; ++j1) {
          int t = 2 * c + j1;
          f4 acc = {0.f, 0.f, 0.f, 0.f};
#pragma unroll
          for (int kk = 0; kk < 3; ++kk) {
            bh8 bf = *(const bh8*)(wf1 + (96 * qq + 16 * t + lq) * CD + 32 * kk + 8 * g);
            acc = __builtin_amdgcn_mfma_f32_16x16x32_bf16(bf, ha[kk], acc, 0, 0, 0);
          }
          float4 bb = *(const float4*)(b_ff1 + 96 * qq + 16 * t + 4 * g);
          vv[2 * j1 + 0] = pk2(gelu_f(acc[0] + bb.x), gelu_f(acc[1] + bb.y));
          vv[2 * j1 + 1] = pk2(gelu_f(acc[2] + bb.z), gelu_f(acc[3] + bb.w));
        }
        xpose4(vv[0], vv[1], vv[2], vv[3]);
        fa[c] = mk8(vv[0], vv[1], vv[2], vv[3]);
      }
#pragma unroll
      for (int t = 0; t < 6; ++t) {
        f4 acc = {0.f, 0.f, 0.f, 0.f};
#pragma unroll
        for (int ks = 0; ks < 3; ++ks) {
          bh8 bf = *(const bh8*)(wf2 + (16 * t + lq) * 384 + 96 * qq + 32 * ks + 8 * g);
          acc = __builtin_amdgcn_mfma_f32_16x16x32_bf16(fa[ks], bf, acc, 0, 0, 0);
        }
#pragma unroll
        for (int r = 0; r < 4; ++r) resid[t][r] += acc[r];
      }
    }
  }

  // ---- store trunk (fp32), reverse window/shift mapping
#pragma unroll
  for (int r = 0; r < 4; ++r) {
    if (16 * w + 4 * g + r < LD) {
#pragma unroll
      for (int t = 0; t < 6; ++t) gout[gbase[r] + 16 * t] = resid[t][r];
    }
  }
}

extern "C" void kernel_launch(void* const* d_in, const int* in_sizes, int n_in,
                              void* d_out, int out_size, void* d_ws, size_t ws_size,
                              hipStream_t stream) {
  cvt_weights<<<432, 256, 0, stream>>>(
      (const float*)d_in[1], (const float*)d_in[3],
      (const float*)d_in[9], (const float*)d_in[11], (u16*)d_ws);
  swin_mfma<<<8192, 256, 0, stream>>>(
      (const float*)d_in[0],                          // x
      (const float*)d_in[2],                          // qkv_b
      (const float*)d_in[4],                          // out_b
      (const float*)d_in[5], (const float*)d_in[6],   // ln1
      (const float*)d_in[7], (const float*)d_in[8],   // ln2
      (const float*)d_in[10], (const float*)d_in[12], // ff1_b, ff2_b
      (const u16*)d_ws, (float*)d_out);
}